// Round 5
// baseline (688.521 us; speedup 1.0000x reference)
//
#include <hip/hip_runtime.h>
#include <hip/hip_bf16.h>

#define FS 24
#define NPATCH 576
#define EMBD 768
#define KDIM 768
#define NB 64
#define IMGW 384
#define MTOT (NB*NPATCH)       // 36864
#define EPSV 1e-4f

#define O2_OFS (MTOT*EMBD)     // 28311552
#define G1_OFS (2*O2_OFS)      // 56623104
#define G2_OFS (G1_OFS + NB*4)

// workspace float-region layout (float indices at byte offset 0)
#define WS_G1 0
#define WS_G2 256
#define WS_SK1 512
#define WS_SK2 576
#define WS_MEAN1 1024
#define WS_STD1 (WS_MEAN1 + NB*EMBD)
#define WS_MEAN2 (WS_STD1 + NB*EMBD)
#define WS_STD2 (WS_MEAN2 + NB*EMBD)

// bf16 W lives at byte offset 1 MiB in ws
#define WSB_W  1048576ULL
#define WS_NEED (WSB_W + 1179648ULL)   // 2,228,224 B

typedef __attribute__((ext_vector_type(8))) short bf16x8;
typedef __attribute__((ext_vector_type(4))) unsigned short u16x4;
typedef __attribute__((ext_vector_type(8))) unsigned short u16x8;
typedef __attribute__((ext_vector_type(4))) float f32x4;

__device__ __forceinline__ u16x4 cvt4_bf16(f32x4 v) {
    u16x4 r;
#pragma unroll
    for (int j = 0; j < 4; ++j) r[j] = __builtin_bit_cast(unsigned short, (__bf16)v[j]);
    return r;
}

// ---------------- boxes: per-batch scalar pipeline (exact f32 port) ----------
__device__ inline float occ_of(const float b1[4], const float b2[4]) {
    float ixmin = fmaxf(b1[0], b2[0]);
    float iymin = fmaxf(b1[1], b2[1]);
    float ixmax = fminf(b1[2], b2[2]);
    float iymax = fminf(b1[3], b2[3]);
    float iv = fmaxf(iymax - iymin, 0.f) * fmaxf(ixmax - ixmin, 0.f);
    float v1 = (b1[2] - b1[0]) * (b1[3] - b1[1]);
    return (iv + 1e-8f) / (v1 + 1e-8f);
}

__device__ inline void upd_box(const float* b1, const float* b2, float* o) {
    float x0 = b1[0], y0 = b1[1], x2 = b1[2], y2 = b1[3];
    float q0 = b2[0], q1 = b2[1], q2 = b2[2], q3 = b2[3];
    bool condA = (x0 >= q0) && (x2 <= q2);
    bool subA1 = (q1 <= y0) && (q3 > y0);
    bool a1 = condA && subA1;
    bool a2 = condA && !subA1 && (q3 >= y2) && (q1 < y2);
    bool condB = !condA && (y0 >= q1) && (y2 <= q3);
    bool subB1 = (q0 <= x0) && (q2 > x0);
    bool bb1 = condB && subB1;
    bool bb2 = condB && !subB1 && (q2 >= x2) && (q0 < x2);
    o[1] = a1 ? q3 : y0;
    o[3] = a2 ? q1 : y2;
    o[0] = bb1 ? q2 : x0;
    o[2] = bb2 ? q0 : x2;
}

__global__ void boxes_kernel(const float* __restrict__ gt1, const float* __restrict__ gt2,
                             float* __restrict__ gout1, float* __restrict__ gout2,
                             float* __restrict__ ws) {
    const int b = threadIdx.x;
    if (b >= NB) return;
    float g1[4], g2[4];
    {
        float p0 = gt1[b*4+0]*(float)IMGW, p1 = gt1[b*4+1]*(float)IMGW;
        float p2 = gt1[b*4+2]*(float)IMGW, p3 = gt1[b*4+3]*(float)IMGW;
        g1[0] = rintf(p0 / 16.f);
        g1[1] = rintf(p1 / 16.f);
        g1[2] = rintf((p0 + p2 - 1.f) / 16.f);
        g1[3] = rintf((p1 + p3 - 1.f) / 16.f);
    }
    {
        float p0 = gt2[b*4+0]*(float)IMGW, p1 = gt2[b*4+1]*(float)IMGW;
        float p2 = gt2[b*4+2]*(float)IMGW, p3 = gt2[b*4+3]*(float)IMGW;
        g2[0] = rintf(p0 / 16.f);
        g2[1] = rintf(p1 / 16.f);
        g2[2] = rintf((p0 + p2 - 1.f) / 16.f);
        g2[3] = rintf((p1 + p3 - 1.f) / 16.f);
    }
    float occ1 = occ_of(g1, g2), occ2 = occ_of(g2, g1);
    const float fsf = (float)FS;
    bool skip1 = (occ1 > 0.5f) || (g2[3] <= g2[1]) || (g2[2] <= g2[0]) ||
                 (g2[0] < 0.f) || (g2[1] < 0.f) || (g2[0] >= fsf) || (g2[1] >= fsf);
    bool skip2 = (occ2 > 0.5f) || (g1[3] <= g1[1]) || (g1[2] <= g1[0]) ||
                 (g1[0] < 0.f) || (g1[1] < 0.f) || (g1[0] >= fsf) || (g1[1] >= fsf);

    float n1[4], n2[4];
    upd_box(g1, g2, n1);
    upd_box(g2, g1, n2);
    if (skip1) { n1[0]=g1[0]; n1[1]=g1[1]; n1[2]=g1[2]; n1[3]=g1[3]; }
    if (skip2) { n2[0]=g2[0]; n2[1]=g2[1]; n2[2]=g2[2]; n2[3]=g2[3]; }

    gout1[b*4+0] = n1[0]; gout1[b*4+1] = n1[1];
    gout1[b*4+2] = n1[2] - n1[0]; gout1[b*4+3] = n1[3] - n1[1];
    gout2[b*4+0] = n2[0]; gout2[b*4+1] = n2[1];
    gout2[b*4+2] = n2[2] - n2[0]; gout2[b*4+3] = n2[3] - n2[1];

#pragma unroll
    for (int i = 0; i < 4; ++i) { ws[WS_G1 + b*4 + i] = g1[i]; ws[WS_G2 + b*4 + i] = g2[i]; }
    ws[WS_SK1 + b] = skip1 ? 1.f : 0.f;
    ws[WS_SK2 + b] = skip2 ? 1.f : 0.f;
}

// ---- pre-convert W f32 -> bf16, LINEAR [n][k] ------------------------------
__global__ void cvt_w_kernel(const float* __restrict__ Wm, unsigned short* __restrict__ Wb) {
    const int idx = blockIdx.x * 256 + threadIdx.x;   // 73728 chunks of 8
    const f32x4 a = *reinterpret_cast<const f32x4*>(Wm + idx*8);
    const f32x4 b = *reinterpret_cast<const f32x4*>(Wm + idx*8 + 4);
    u16x8 r;
    u16x4 lo = cvt4_bf16(a), hi = cvt4_bf16(b);
#pragma unroll
    for (int j = 0; j < 4; ++j) { r[j] = lo[j]; r[j+4] = hi[j]; }
    *reinterpret_cast<u16x8*>(Wb + idx*8) = r;
}

// ---- fused im2col + bf16 GEMM, 4-deep register pipeline --------------------
// 128x128 tile, BK=64, 4 waves, dbuf LDS (64 KiB), reg sets S0..S3:
// step kt: LDS-write tile kt+1 (loaded 3 steps ago) -> issue loads kt+4 ->
// MFMA buf(kt&1) -> lgkmcnt(0)+s_barrier (vmcnt NOT drained at barriers).
#define ISSUE_LOADS(SET, KT4)                                                      \
    {                                                                              \
      const int dA = ((KT4) >> 2)*(IMGW*IMGW) + ((KT4) & 3)*(4*IMGW);              \
      _Pragma("unroll")                                                            \
      for (int j = 0; j < 4; ++j) {                                                \
        SET##A[j][0] = *reinterpret_cast<const f32x4*>(xin + boffA[j] + dA);       \
        SET##A[j][1] = *reinterpret_cast<const f32x4*>(xin + boffA[j] + dA + 4);   \
        SET##B[j]    = *reinterpret_cast<const u16x8*>(Wb + boffB[j] + (KT4)*64);  \
      }                                                                            \
    }

#define LDS_WRITE(SET, DBUF)                                                       \
    {                                                                              \
      unsigned char* Aw = ldsA + (DBUF)*16384;                                     \
      unsigned char* Bw = ldsB + (DBUF)*16384;                                     \
      _Pragma("unroll")                                                            \
      for (int j = 0; j < 4; ++j) {                                                \
        u16x4 lo = cvt4_bf16(SET##A[j][0]), hi = cvt4_bf16(SET##A[j][1]);          \
        u16x8 v;                                                                   \
        _Pragma("unroll")                                                          \
        for (int q = 0; q < 4; ++q) { v[q] = lo[q]; v[q+4] = hi[q]; }              \
        *reinterpret_cast<u16x8*>(Aw + lofsA[j]) = v;                              \
        *reinterpret_cast<u16x8*>(Bw + lofsA[j]) = SET##B[j];                      \
      }                                                                            \
    }

#define GEMM_STEP(KT, SW, SL, CBUF)                                                \
  {                                                                                \
    const int kt_ = (KT);                                                          \
    if (kt_ + 1 < 12) LDS_WRITE(SW, (CBUF)^1)                                      \
    if (kt_ + 4 < 12) ISSUE_LOADS(SL, kt_ + 4)                                     \
    {                                                                              \
      const unsigned char* Ar = ldsA + (CBUF)*16384;                               \
      const unsigned char* Br = ldsB + (CBUF)*16384;                               \
      _Pragma("unroll")                                                            \
      for (int ko = 0; ko < 2; ++ko) {                                             \
        const int colb = ko*64 + fq*16;                                            \
        bf16x8 af[4], bfv[4];                                                      \
        _Pragma("unroll")                                                          \
        for (int i = 0; i < 4; ++i) {                                              \
          af[i]  = *reinterpret_cast<const bf16x8*>(Ar + (wr*64 + i*16 + fr)*128 + (colb ^ xorv)); \
          bfv[i] = *reinterpret_cast<const bf16x8*>(Br + (wc*64 + i*16 + fr)*128 + (colb ^ xorv)); \
        }                                                                          \
        __builtin_amdgcn_s_setprio(1);                                             \
        _Pragma("unroll")                                                          \
        for (int mi = 0; mi < 4; ++mi)                                             \
          _Pragma("unroll")                                                        \
          for (int ni = 0; ni < 4; ++ni)                                           \
            acc[mi][ni] = __builtin_amdgcn_mfma_f32_16x16x32_bf16(                 \
                af[mi], bfv[ni], acc[mi][ni], 0, 0, 0);                            \
        __builtin_amdgcn_s_setprio(0);                                             \
      }                                                                            \
    }                                                                              \
    asm volatile("s_waitcnt lgkmcnt(0)\n\ts_barrier" ::: "memory");                \
  }

__global__ __launch_bounds__(256, 2)
void fused_gemm_kernel(const float* __restrict__ x1, const float* __restrict__ xx2,
                       const unsigned short* __restrict__ Wb,
                       const float* __restrict__ bias,
                       float* __restrict__ out) {
    __shared__ __align__(16) unsigned char ldsA[2*16384];
    __shared__ __align__(16) unsigned char ldsB[2*16384];

    const float* __restrict__ xin = blockIdx.y ? xx2 : x1;
    float* __restrict__ oo = out + (size_t)blockIdx.y * (size_t)O2_OFS;

    const int bx = blockIdx.x;
    const int swz = (bx & 7) * 216 + (bx >> 3);
    const int mt = swz / 6;
    const int nt = swz - mt * 6;
    const int m0 = mt * 128;
    const int n0 = nt * 128;

    const int tid = threadIdx.x;

    int boffA[4], lofsA[4], boffB[4];
#pragma unroll
    for (int j = 0; j < 4; ++j) {
        const int ci = tid + 256*j;          // 0..1023
        const int row = ci >> 3, c8 = ci & 7;
        const int m = m0 + row;
        const int bb = m / NPATCH;
        const int p  = m - bb*NPATCH;
        const int py = p / FS, px = p - py*FS;
        boffA[j] = ((bb*3)*IMGW + py*16 + (c8 >> 1)) * IMGW + px*16 + (c8 & 1)*8;
        lofsA[j] = (ci*16) ^ ((row & 7) << 4);
        boffB[j] = (n0 + row)*KDIM + c8*8;
    }

    f32x4 acc[4][4];
#pragma unroll
    for (int i = 0; i < 4; ++i)
#pragma unroll
        for (int j = 0; j < 4; ++j) acc[i][j] = (f32x4){0.f, 0.f, 0.f, 0.f};

    const int l  = tid & 63;
    const int wid = tid >> 6;
    const int wr = wid >> 1, wc = wid & 1;
    const int fr = l & 15, fq = l >> 4;
    const int xorv = (fr & 7) << 4;

    // 4 register staging sets
    f32x4 S0A[4][2], S1A[4][2], S2A[4][2], S3A[4][2];
    u16x8 S0B[4], S1B[4], S2B[4], S3B[4];

    // prologue: issue loads for tiles 0..3, write tile 0 -> buf0
    ISSUE_LOADS(S0, 0)
    ISSUE_LOADS(S1, 1)
    ISSUE_LOADS(S2, 2)
    ISSUE_LOADS(S3, 3)
    LDS_WRITE(S0, 0)
    asm volatile("s_waitcnt lgkmcnt(0)\n\ts_barrier" ::: "memory");

    for (int kt = 0; kt < 12; kt += 4) {
        GEMM_STEP(kt,   S1, S0, 0)
        GEMM_STEP(kt+1, S2, S1, 1)
        GEMM_STEP(kt+2, S3, S2, 0)
        GEMM_STEP(kt+3, S0, S3, 1)
    }

    // epilogue
#pragma unroll
    for (int ni = 0; ni < 4; ++ni) {
        const int col = n0 + wc*64 + ni*16 + fr;
        const float bv = bias[col];
#pragma unroll
        for (int mi = 0; mi < 4; ++mi) {
            const int rowb = m0 + wr*64 + mi*16 + fq*4;
#pragma unroll
            for (int r = 0; r < 4; ++r)
                oo[(size_t)(rowb + r)*EMBD + col] = acc[mi][ni][r] + bv;
        }
    }
}

// ---------------- FALLBACK GEMM (round-0, f32 reg-staged, 2-barrier) --------
__global__ __launch_bounds__(256, 2)
void embed_gemm_kernel(const float* __restrict__ x1, const float* __restrict__ xx2,
                       const float* __restrict__ Wm, const float* __restrict__ bias,
                       float* __restrict__ out) {
    __shared__ __align__(16) unsigned char As[128*64*2];
    __shared__ __align__(16) unsigned char Bs[128*64*2];

    const float* __restrict__ xin = blockIdx.y ? xx2 : x1;
    float* __restrict__ oo = out + (size_t)blockIdx.y * (size_t)O2_OFS;

    const int bx = blockIdx.x;
    const int swz = (bx & 7) * (1728/8) + (bx >> 3);
    const int mt = swz / 6;
    const int nt = swz - mt * 6;
    const int m0 = mt * 128;
    const int n0 = nt * 128;

    const int tid = threadIdx.x;

    int boffA[8], boffB[8], lofs[8];
#pragma unroll
    for (int it = 0; it < 8; ++it) {
        const int ci = tid + 256*it;
        const int row = ci >> 4, col4 = ci & 15;
        const int m = m0 + row;
        const int bb = m / NPATCH;
        const int p  = m - bb*NPATCH;
        const int py = p / FS, px = p - py*FS;
        boffA[it] = ((bb*3)*IMGW + py*16 + (col4 >> 2)) * IMGW + px*16 + (col4 & 3)*4;
        boffB[it] = (n0 + row)*KDIM + col4*4;
        lofs[it]  = (ci*8) ^ ((row & 7) << 4);
    }

    f32x4 acc[4][4];
#pragma unroll
    for (int i = 0; i < 4; ++i)
#pragma unroll
        for (int j = 0; j < 4; ++j) acc[i][j] = (f32x4){0.f, 0.f, 0.f, 0.f};

    f32x4 stA[8], stB[8];
#pragma unroll
    for (int it = 0; it < 8; ++it) {
        stA[it] = *reinterpret_cast<const f32x4*>(xin + boffA[it]);
        stB[it] = *reinterpret_cast<const f32x4*>(Wm + boffB[it]);
    }

    const int l  = tid & 63;
    const int wid = tid >> 6;
    const int wr = wid >> 1, wc = wid & 1;
    const int fr = l & 15, fq = l >> 4;
    const int xorv = (fr & 7) << 4;

    for (int kt = 0; kt < 12; ++kt) {
        __syncthreads();
#pragma unroll
        for (int it = 0; it < 8; ++it) {
            *reinterpret_cast<u16x4*>(As + lofs[it]) = cvt4_bf16(stA[it]);
            *reinterpret_cast<u16x4*>(Bs + lofs[it]) = cvt4_bf16(stB[it]);
        }
        if (kt + 1 < 12) {
            const int dA = ((kt+1) >> 2) * (IMGW*IMGW) + ((kt+1) & 3) * (4*IMGW);
            const int dB = (kt+1) * 64;
#pragma unroll
            for (int it = 0; it < 8; ++it) {
                stA[it] = *reinterpret_cast<const f32x4*>(xin + boffA[it] + dA);
                stB[it] = *reinterpret_cast<const f32x4*>(Wm + boffB[it] + dB);
            }
        }
        __syncthreads();
#pragma unroll
        for (int ko = 0; ko < 2; ++ko) {
            const int colb = ko*64 + fq*16;
            bf16x8 af[4], bf4[4];
#pragma unroll
            for (int i = 0; i < 4; ++i) {
                af[i]  = *reinterpret_cast<const bf16x8*>(As + (wr*64 + i*16 + fr)*128 + (colb ^ xorv));
                bf4[i] = *reinterpret_cast<const bf16x8*>(Bs + (wc*64 + i*16 + fr)*128 + (colb ^ xorv));
            }
#pragma unroll
            for (int mi = 0; mi < 4; ++mi)
#pragma unroll
                for (int ni = 0; ni < 4; ++ni)
                    acc[mi][ni] = __builtin_amdgcn_mfma_f32_16x16x32_bf16(
                        af[mi], bf4[ni], acc[mi][ni], 0, 0, 0);
        }
    }

#pragma unroll
    for (int ni = 0; ni < 4; ++ni) {
        const int col = n0 + wc*64 + ni*16 + fr;
        const float bv = bias[col];
#pragma unroll
        for (int mi = 0; mi < 4; ++mi) {
            const int rowb = m0 + wr*64 + mi*16 + fq*4;
#pragma unroll
            for (int r = 0; r < 4; ++r)
                oo[(size_t)(rowb + r)*EMBD + col] = acc[mi][ni][r] + bv;
        }
    }
}

// ---------------- masked per-channel stats ----------------------------------
__global__ void stats_kernel(const float* __restrict__ o1, const float* __restrict__ o2,
                             float* __restrict__ ws) {
    const int b = blockIdx.y;
    const int c = blockIdx.x * 256 + threadIdx.x;

    float g1[4], g2[4];
#pragma unroll
    for (int i = 0; i < 4; ++i) { g1[i] = ws[WS_G1 + b*4 + i]; g2[i] = ws[WS_G2 + b*4 + i]; }

    for (int t = 0; t < 2; ++t) {
        const float* f = t ? o2 : o1;
        const float* g = t ? g2 : g1;
        int xlo = max(0, (int)g[0]);
        int xhi = min(FS, (int)g[2]);
        int ylo = max(0, (int)g[1]);
        int yhi = min(FS, (int)g[3]);
        float s = 0.f, ss = 0.f;
        for (int py = ylo; py < yhi; ++py)
            for (int px = xlo; px < xhi; ++px) {
                float v = f[(size_t)(b*NPATCH + py*FS + px)*EMBD + c];
                s += v; ss += v*v;
            }
        int nx = xhi - xlo; if (nx < 0) nx = 0;
        int ny = yhi - ylo; if (ny < 0) ny = 0;
        float n = (float)(nx*ny);
        float mean = s / fmaxf(n, 1.f);
        float var = (ss - 2.f*mean*s + n*mean*mean) / fmaxf(n - 1.f, 1.f);
        float sd = sqrtf(fmaxf(var, 0.f));
        ws[(t ? WS_MEAN2 : WS_MEAN1) + b*EMBD + c] = mean;
        ws[(t ? WS_STD2 : WS_STD1) + b*EMBD + c] = sd;
    }
}

// ---------------- blend (read-own / write-own, race-free) -------------------
__global__ void blend_kernel(float* __restrict__ o1, float* __restrict__ o2,
                             const float* __restrict__ ws) {
    const int b = blockIdx.y;
    const int p = blockIdx.x;
    const int py = p / FS, px = p - py*FS;
    const float pxf = (float)px, pyf = (float)py;

    const float sk1 = ws[WS_SK1 + b];
    const float sk2 = ws[WS_SK2 + b];
    const bool in1 = (pxf >= ws[WS_G1 + b*4+0]) && (pxf < ws[WS_G1 + b*4+2]) &&
                     (pyf >= ws[WS_G1 + b*4+1]) && (pyf < ws[WS_G1 + b*4+3]);
    const bool in2 = (pxf >= ws[WS_G2 + b*4+0]) && (pxf < ws[WS_G2 + b*4+2]) &&
                     (pyf >= ws[WS_G2 + b*4+1]) && (pyf < ws[WS_G2 + b*4+3]);
    const bool do1 = (sk1 == 0.f) && in2;
    const bool do2 = (sk2 == 0.f) && in1;
    if (!do1 && !do2) return;

    const int c = threadIdx.x * 4;
    const size_t base = (size_t)(b*NPATCH + p)*EMBD + c;
    const f32x4 f1 = *reinterpret_cast<const f32x4*>(o1 + base);
    const f32x4 f2 = *reinterpret_cast<const f32x4*>(o2 + base);
    const f32x4 m1 = *reinterpret_cast<const f32x4*>(ws + WS_MEAN1 + b*EMBD + c);
    const f32x4 s1 = *reinterpret_cast<const f32x4*>(ws + WS_STD1  + b*EMBD + c);
    const f32x4 m2 = *reinterpret_cast<const f32x4*>(ws + WS_MEAN2 + b*EMBD + c);
    const f32x4 s2 = *reinterpret_cast<const f32x4*>(ws + WS_STD2  + b*EMBD + c);

    if (do1) {
        f32x4 r;
#pragma unroll
        for (int j = 0; j < 4; ++j)
            r[j] = (f2[j] - m2[j]) / (s2[j] + EPSV) * (s1[j] + EPSV) + m1[j];
        *reinterpret_cast<f32x4*>(o1 + base) = r;
    }
    if (do2) {
        f32x4 r;
#pragma unroll
        for (int j = 0; j < 4; ++j)
            r[j] = (f1[j] - m1[j]) / (s1[j] + EPSV) * (s2[j] + EPSV) + m2[j];
        *reinterpret_cast<f32x4*>(o2 + base) = r;
    }
}

extern "C" void kernel_launch(void* const* d_in, const int* in_sizes, int n_in,
                              void* d_out, int out_size, void* d_ws, size_t ws_size,
                              hipStream_t stream) {
    const float* x    = (const float*)d_in[0];
    const float* x2   = (const float*)d_in[1];
    const float* gt1  = (const float*)d_in[2];
    const float* gt2  = (const float*)d_in[3];
    const float* Wm   = (const float*)d_in[4];
    const float* bias = (const float*)d_in[5];
    float* out = (float*)d_out;
    float* ws  = (float*)d_ws;

    float* o1 = out;
    float* o2 = out + O2_OFS;
    float* g1n = out + G1_OFS;
    float* g2n = out + G2_OFS;

    boxes_kernel<<<1, 64, 0, stream>>>(gt1, gt2, g1n, g2n, ws);

    if (ws_size >= WS_NEED) {
        unsigned short* Wb = (unsigned short*)((char*)d_ws + WSB_W);
        cvt_w_kernel<<<288, 256, 0, stream>>>(Wm, Wb);
        fused_gemm_kernel<<<dim3(1728, 2), 256, 0, stream>>>(x, x2, Wb, bias, out);
    } else {
        embed_gemm_kernel<<<dim3(1728, 2), 256, 0, stream>>>(x, x2, Wm, bias, out);
    }

    stats_kernel<<<dim3(3, NB), 256, 0, stream>>>(o1, o2, ws);
    blend_kernel<<<dim3(NPATCH, NB), 192, 0, stream>>>(o1, o2, ws);
}

// Round 6
// 281.801 us; speedup vs baseline: 2.4433x; 2.4433x over previous
//
#include <hip/hip_runtime.h>
#include <hip/hip_bf16.h>

#define FS 24
#define NPATCH 576
#define EMBD 768
#define KDIM 768
#define NB 64
#define IMGW 384
#define MTOT (NB*NPATCH)       // 36864
#define EPSV 1e-4f

#define O2_OFS (MTOT*EMBD)     // 28311552
#define G1_OFS (2*O2_OFS)      // 56623104
#define G2_OFS (G1_OFS + NB*4)

// workspace float-region layout (float indices at byte offset 0)
#define WS_G1 0
#define WS_G2 256
#define WS_SK1 512
#define WS_SK2 576
#define WS_MEAN1 1024
#define WS_STD1 (WS_MEAN1 + NB*EMBD)
#define WS_MEAN2 (WS_STD1 + NB*EMBD)
#define WS_STD2 (WS_MEAN2 + NB*EMBD)

// bf16 W (chunk-swizzled) at byte offset 1 MiB in ws
#define WSB_W  1048576ULL
#define WS_NEED (WSB_W + 1179648ULL)   // 2,228,224 B  (proven available r3/r4)

typedef __attribute__((ext_vector_type(8))) short bf16x8;
typedef __attribute__((ext_vector_type(4))) unsigned short u16x4;
typedef __attribute__((ext_vector_type(8))) unsigned short u16x8;
typedef __attribute__((ext_vector_type(4))) float f32x4;

__device__ __forceinline__ u16x4 cvt4_bf16(f32x4 v) {
    u16x4 r;
#pragma unroll
    for (int j = 0; j < 4; ++j) r[j] = __builtin_bit_cast(unsigned short, (__bf16)v[j]);
    return r;
}

__device__ __forceinline__ void gload16(const void* g, const void* l) {
    __builtin_amdgcn_global_load_lds(
        (const __attribute__((address_space(1))) unsigned int*)g,
        (__attribute__((address_space(3))) unsigned int*)l, 16, 0, 0);
}

// ---------------- boxes ------------------------------------------------------
__device__ inline float occ_of(const float b1[4], const float b2[4]) {
    float ixmin = fmaxf(b1[0], b2[0]);
    float iymin = fmaxf(b1[1], b2[1]);
    float ixmax = fminf(b1[2], b2[2]);
    float iymax = fminf(b1[3], b2[3]);
    float iv = fmaxf(iymax - iymin, 0.f) * fmaxf(ixmax - ixmin, 0.f);
    float v1 = (b1[2] - b1[0]) * (b1[3] - b1[1]);
    return (iv + 1e-8f) / (v1 + 1e-8f);
}

__device__ inline void upd_box(const float* b1, const float* b2, float* o) {
    float x0 = b1[0], y0 = b1[1], x2 = b1[2], y2 = b1[3];
    float q0 = b2[0], q1 = b2[1], q2 = b2[2], q3 = b2[3];
    bool condA = (x0 >= q0) && (x2 <= q2);
    bool subA1 = (q1 <= y0) && (q3 > y0);
    bool a1 = condA && subA1;
    bool a2 = condA && !subA1 && (q3 >= y2) && (q1 < y2);
    bool condB = !condA && (y0 >= q1) && (y2 <= q3);
    bool subB1 = (q0 <= x0) && (q2 > x0);
    bool bb1 = condB && subB1;
    bool bb2 = condB && !subB1 && (q2 >= x2) && (q0 < x2);
    o[1] = a1 ? q3 : y0;
    o[3] = a2 ? q1 : y2;
    o[0] = bb1 ? q2 : x0;
    o[2] = bb2 ? q0 : x2;
}

__global__ void boxes_kernel(const float* __restrict__ gt1, const float* __restrict__ gt2,
                             float* __restrict__ gout1, float* __restrict__ gout2,
                             float* __restrict__ ws) {
    const int b = threadIdx.x;
    if (b >= NB) return;
    float g1[4], g2[4];
    {
        float p0 = gt1[b*4+0]*(float)IMGW, p1 = gt1[b*4+1]*(float)IMGW;
        float p2 = gt1[b*4+2]*(float)IMGW, p3 = gt1[b*4+3]*(float)IMGW;
        g1[0] = rintf(p0 / 16.f);
        g1[1] = rintf(p1 / 16.f);
        g1[2] = rintf((p0 + p2 - 1.f) / 16.f);
        g1[3] = rintf((p1 + p3 - 1.f) / 16.f);
    }
    {
        float p0 = gt2[b*4+0]*(float)IMGW, p1 = gt2[b*4+1]*(float)IMGW;
        float p2 = gt2[b*4+2]*(float)IMGW, p3 = gt2[b*4+3]*(float)IMGW;
        g2[0] = rintf(p0 / 16.f);
        g2[1] = rintf(p1 / 16.f);
        g2[2] = rintf((p0 + p2 - 1.f) / 16.f);
        g2[3] = rintf((p1 + p3 - 1.f) / 16.f);
    }
    float occ1 = occ_of(g1, g2), occ2 = occ_of(g2, g1);
    const float fsf = (float)FS;
    bool skip1 = (occ1 > 0.5f) || (g2[3] <= g2[1]) || (g2[2] <= g2[0]) ||
                 (g2[0] < 0.f) || (g2[1] < 0.f) || (g2[0] >= fsf) || (g2[1] >= fsf);
    bool skip2 = (occ2 > 0.5f) || (g1[3] <= g1[1]) || (g1[2] <= g1[0]) ||
                 (g1[0] < 0.f) || (g1[1] < 0.f) || (g1[0] >= fsf) || (g1[1] >= fsf);

    float n1[4], n2[4];
    upd_box(g1, g2, n1);
    upd_box(g2, g1, n2);
    if (skip1) { n1[0]=g1[0]; n1[1]=g1[1]; n1[2]=g1[2]; n1[3]=g1[3]; }
    if (skip2) { n2[0]=g2[0]; n2[1]=g2[1]; n2[2]=g2[2]; n2[3]=g2[3]; }

    gout1[b*4+0] = n1[0]; gout1[b*4+1] = n1[1];
    gout1[b*4+2] = n1[2] - n1[0]; gout1[b*4+3] = n1[3] - n1[1];
    gout2[b*4+0] = n2[0]; gout2[b*4+1] = n2[1];
    gout2[b*4+2] = n2[2] - n2[0]; gout2[b*4+3] = n2[3] - n2[1];

#pragma unroll
    for (int i = 0; i < 4; ++i) { ws[WS_G1 + b*4 + i] = g1[i]; ws[WS_G2 + b*4 + i] = g2[i]; }
    ws[WS_SK1 + b] = skip1 ? 1.f : 0.f;
    ws[WS_SK2 + b] = skip2 ? 1.f : 0.f;
}

// ---- pre-convert W f32 -> bf16, chunk-swizzled within each 64-elem k-block:
// original chunk c8 stored at position c8 ^ (n&7). gload_lds copies linearly;
// the GEMM ds_read applies the same XOR -> round-trips correctly (T2/m201).
__global__ void cvt_w_kernel(const float* __restrict__ Wm, unsigned short* __restrict__ Wb) {
    const int idx = blockIdx.x * 256 + threadIdx.x;   // 73728 = 768 rows * 96 chunks
    const int n = idx / 96;
    const int c = idx - n * 96;
    const f32x4 a = *reinterpret_cast<const f32x4*>(Wm + idx*8);
    const f32x4 b = *reinterpret_cast<const f32x4*>(Wm + idx*8 + 4);
    u16x8 r;
    u16x4 lo = cvt4_bf16(a), hi = cvt4_bf16(b);
#pragma unroll
    for (int j = 0; j < 4; ++j) { r[j] = lo[j]; r[j+4] = hi[j]; }
    const int pos = ((c >> 3) << 6) + (((c & 7) ^ (n & 7)) << 3);
    *reinterpret_cast<u16x8*>(Wb + (size_t)n*KDIM + pos) = r;
}

// ---- fused im2col + bf16 GEMM ----------------------------------------------
// BM=128 BN=128 BK=64, 512 thr (8 waves, 2 wr x 4 wc, per-wave 64x32 out).
// A: reg-staged 3 sets (2-step issue->consume distance), cvt f32->bf16, XOR-swz
//    ds_write. B: global_load_lds from pre-swizzled Wb (0 regs), dbuf.
// Fully unrolled 12 K-steps; counted vmcnt only (never drain in steady state).

#define LOAD_A(SI, T)                                                              \
    { const int dA_ = ((T) >> 2)*(IMGW*IMGW) + ((T) & 3)*(4*IMGW);                 \
      S[SI][0] = *reinterpret_cast<const f32x4*>(xin + aoff0 + dA_);               \
      S[SI][1] = *reinterpret_cast<const f32x4*>(xin + aoff0 + dA_ + 4);           \
      S[SI][2] = *reinterpret_cast<const f32x4*>(xin + aoff1 + dA_);               \
      S[SI][3] = *reinterpret_cast<const f32x4*>(xin + aoff1 + dA_ + 4); }

#define WRITE_A(SI, WB)                                                            \
    { u16x4 lo0 = cvt4_bf16(S[SI][0]), hi0 = cvt4_bf16(S[SI][1]);                  \
      u16x4 lo1 = cvt4_bf16(S[SI][2]), hi1 = cvt4_bf16(S[SI][3]);                  \
      u16x8 v0, v1;                                                                \
      _Pragma("unroll")                                                            \
      for (int q = 0; q < 4; ++q) { v0[q]=lo0[q]; v0[q+4]=hi0[q];                  \
                                    v1[q]=lo1[q]; v1[q+4]=hi1[q]; }                \
      *reinterpret_cast<u16x8*>(ldsA + (WB)*16384 + lws0) = v0;                    \
      *reinterpret_cast<u16x8*>(ldsA + (WB)*16384 + lws1) = v1; }

#define FSTEP(KT, VMC)                                                             \
  {                                                                                \
    /* p1: fragment ds_reads from buf (KT&1) */                                    \
    bf16x8 af[4][2], bfv[2][2];                                                    \
    _Pragma("unroll")                                                              \
    for (int mi = 0; mi < 4; ++mi) {                                               \
      const int r_ = wr*64 + mi*16 + fr;                                           \
      _Pragma("unroll")                                                            \
      for (int ko = 0; ko < 2; ++ko)                                               \
        af[mi][ko] = *reinterpret_cast<const bf16x8*>(                             \
            ldsA + ((KT)&1)*16384 + r_*128 + ((ko*64 + fq*16) ^ ((r_&7)<<4)));     \
    }                                                                              \
    _Pragma("unroll")                                                              \
    for (int ni = 0; ni < 2; ++ni) {                                               \
      const int r_ = wc*32 + ni*16 + fr;                                           \
      _Pragma("unroll")                                                            \
      for (int ko = 0; ko < 2; ++ko)                                               \
        bfv[ni][ko] = *reinterpret_cast<const bf16x8*>(                            \
            ldsB + ((KT)&1)*16384 + r_*128 + ((ko*64 + fq*16) ^ ((r_&7)<<4)));     \
    }                                                                              \
    /* p2: all waves done reading both bufs */                                     \
    asm volatile("s_waitcnt lgkmcnt(0)\ns_barrier" ::: "memory");                  \
    __builtin_amdgcn_sched_barrier(0);                                             \
    /* p3: ds_write A(KT+1) (loaded 2 steps ago; auto-vmcnt keeps newer loads) */  \
    if ((KT) + 1 < 12) WRITE_A(((KT)+1)%3, ((KT)&1)^1)                             \
    /* p4: DMA B(KT+2) into Bbuf[KT&1] (its reads finished at p2) */               \
    if ((KT) + 2 < 12) {                                                           \
      gload16(bsrc0 + ((KT)+2)*128, ldsB + ((KT)&1)*16384 + wuni);                 \
      gload16(bsrc1 + ((KT)+2)*128, ldsB + ((KT)&1)*16384 + 8192 + wuni);          \
    }                                                                              \
    /* p5: issue A(KT+3) loads into set KT%3 */                                    \
    if ((KT) + 3 < 12) LOAD_A((KT)%3, (KT)+3)                                      \
    /* p6: MFMA */                                                                 \
    __builtin_amdgcn_s_setprio(1);                                                 \
    _Pragma("unroll")                                                              \
    for (int mi = 0; mi < 4; ++mi)                                                 \
      _Pragma("unroll")                                                            \
      for (int ni = 0; ni < 2; ++ni)                                               \
        _Pragma("unroll")                                                          \
        for (int ko = 0; ko < 2; ++ko)                                             \
          acc[mi][ni] = __builtin_amdgcn_mfma_f32_16x16x32_bf16(                   \
              af[mi][ko], bfv[ni][ko], acc[mi][ni], 0, 0, 0);                      \
    __builtin_amdgcn_s_setprio(0);                                                 \
    /* p7/8: B(KT+1) landed + A-writes visible; keep VMC ops in flight */          \
    if ((KT) < 11) {                                                               \
      asm volatile("s_waitcnt vmcnt(" #VMC ") lgkmcnt(0)\ns_barrier" ::: "memory");\
      __builtin_amdgcn_sched_barrier(0);                                           \
    }                                                                              \
  }

__global__ __launch_bounds__(512, 2)
void fused_gemm_kernel(const float* __restrict__ x1, const float* __restrict__ xx2,
                       const unsigned short* __restrict__ Wb,
                       const float* __restrict__ bias,
                       float* __restrict__ out) {
    __shared__ __align__(16) unsigned char ldsA[2*16384];
    __shared__ __align__(16) unsigned char ldsB[2*16384];

    const float* __restrict__ xin = blockIdx.y ? xx2 : x1;
    float* __restrict__ oo = out + (size_t)blockIdx.y * (size_t)O2_OFS;

    const int bx = blockIdx.x;                 // 1728 = 8 * 216
    const int swz = (bx & 7) * 216 + (bx >> 3);
    const int mt = swz / 6;
    const int nt = swz - mt * 6;
    const int m0 = mt * 128;
    const int n0 = nt * 128;

    const int tid  = threadIdx.x;
    const int lane = tid & 63;
    const int wid  = tid >> 6;
    const int wr = wid >> 2, wc = wid & 3;     // 2 x 4 waves, per-wave 64x32
    const int fr = lane & 15, fq = lane >> 4;

    // ---- A staging addressing: 1024 chunks of 8 k-elems; this thread owns
    // chunks tid and tid+512 (rows tid>>3 and +64).
    int aoff0, aoff1, lws0, lws1;
    {
        const int c0 = tid, c1 = tid + 512;
        const int r0 = c0 >> 3, c80 = c0 & 7;
        const int r1 = c1 >> 3, c81 = c1 & 7;
        const int m_0 = m0 + r0, m_1 = m0 + r1;
        const int bb0 = m_0 / NPATCH, p_0 = m_0 - bb0*NPATCH;
        const int bb1 = m_1 / NPATCH, p_1 = m_1 - bb1*NPATCH;
        const int py0 = p_0 / FS, px0 = p_0 - py0*FS;
        const int py1 = p_1 / FS, px1 = p_1 - py1*FS;
        aoff0 = ((bb0*3)*IMGW + py0*16 + (c80 >> 1)) * IMGW + px0*16 + (c80 & 1)*8;
        aoff1 = ((bb1*3)*IMGW + py1*16 + (c81 >> 1)) * IMGW + px1*16 + (c81 & 1)*8;
        lws0 = (c0*16) ^ ((r0 & 7) << 4);
        lws1 = (c1*16) ^ ((r1 & 7) << 4);
    }
    // ---- B staging: per-lane source (pre-swizzled Wb), wave-uniform LDS dest
    const char* bsrc0;
    const char* bsrc1;
    const int wuni = wid * 1024;
    {
        const int br0 = tid >> 3, bc8 = tid & 7;
        bsrc0 = (const char*)Wb + (size_t)(n0 + br0)*1536 + bc8*16;
        bsrc1 = bsrc0 + 64*1536;
    }

    f32x4 acc[4][2];
#pragma unroll
    for (int i = 0; i < 4; ++i)
#pragma unroll
        for (int j = 0; j < 2; ++j) acc[i][j] = (f32x4){0.f, 0.f, 0.f, 0.f};

    f32x4 S[3][4];

    // ---- prologue: A0,B0,B1,A1,A2 in flight; write A0; drain A0+B0 only ----
    LOAD_A(0, 0)
    gload16(bsrc0,       ldsB + wuni);
    gload16(bsrc1,       ldsB + 8192 + wuni);
    gload16(bsrc0 + 128, ldsB + 16384 + wuni);
    gload16(bsrc1 + 128, ldsB + 16384 + 8192 + wuni);
    LOAD_A(1, 1)
    LOAD_A(2, 2)
    WRITE_A(0, 0)                               // auto-wait drains A0 only
    asm volatile("s_waitcnt vmcnt(10) lgkmcnt(0)\ns_barrier" ::: "memory"); // +B0
    __builtin_amdgcn_sched_barrier(0);

    FSTEP(0, 10)  FSTEP(1, 10)  FSTEP(2, 10)  FSTEP(3, 10)
    FSTEP(4, 10)  FSTEP(5, 10)  FSTEP(6, 10)  FSTEP(7, 10)
    FSTEP(8, 10)  FSTEP(9, 6)   FSTEP(10, 0)  FSTEP(11, 0)

    // ---- epilogue ----
#pragma unroll
    for (int ni = 0; ni < 2; ++ni) {
        const int col = n0 + wc*32 + ni*16 + fr;
        const float bv = bias[col];
#pragma unroll
        for (int mi = 0; mi < 4; ++mi) {
            const int rowb = m0 + wr*64 + mi*16 + fq*4;
#pragma unroll
            for (int r = 0; r < 4; ++r)
                oo[(size_t)(rowb + r)*EMBD + col] = acc[mi][ni][r] + bv;
        }
    }
}

// ---------------- FALLBACK GEMM (round-0, known-good 222 us) ----------------
__global__ __launch_bounds__(256, 2)
void embed_gemm_kernel(const float* __restrict__ x1, const float* __restrict__ xx2,
                       const float* __restrict__ Wm, const float* __restrict__ bias,
                       float* __restrict__ out) {
    __shared__ __align__(16) unsigned char As[128*64*2];
    __shared__ __align__(16) unsigned char Bs[128*64*2];

    const float* __restrict__ xin = blockIdx.y ? xx2 : x1;
    float* __restrict__ oo = out + (size_t)blockIdx.y * (size_t)O2_OFS;

    const int bx = blockIdx.x;
    const int swz = (bx & 7) * (1728/8) + (bx >> 3);
    const int mt = swz / 6;
    const int nt = swz - mt * 6;
    const int m0 = mt * 128;
    const int n0 = nt * 128;

    const int tid = threadIdx.x;

    int boffA[8], boffB[8], lofs[8];
#pragma unroll
    for (int it = 0; it < 8; ++it) {
        const int ci = tid + 256*it;
        const int row = ci >> 4, col4 = ci & 15;
        const int m = m0 + row;
        const int bb = m / NPATCH;
        const int p  = m - bb*NPATCH;
        const int py = p / FS, px = p - py*FS;
        boffA[it] = ((bb*3)*IMGW + py*16 + (col4 >> 2)) * IMGW + px*16 + (col4 & 3)*4;
        boffB[it] = (n0 + row)*KDIM + col4*4;
        lofs[it]  = (ci*8) ^ ((row & 7) << 4);
    }

    f32x4 acc[4][4];
#pragma unroll
    for (int i = 0; i < 4; ++i)
#pragma unroll
        for (int j = 0; j < 4; ++j) acc[i][j] = (f32x4){0.f, 0.f, 0.f, 0.f};

    f32x4 stA[8], stB[8];
#pragma unroll
    for (int it = 0; it < 8; ++it) {
        stA[it] = *reinterpret_cast<const f32x4*>(xin + boffA[it]);
        stB[it] = *reinterpret_cast<const f32x4*>(Wm + boffB[it]);
    }

    const int l  = tid & 63;
    const int wid = tid >> 6;
    const int wr = wid >> 1, wc = wid & 1;
    const int fr = l & 15, fq = l >> 4;
    const int xorv = (fr & 7) << 4;

    for (int kt = 0; kt < 12; ++kt) {
        __syncthreads();
#pragma unroll
        for (int it = 0; it < 8; ++it) {
            *reinterpret_cast<u16x4*>(As + lofs[it]) = cvt4_bf16(stA[it]);
            *reinterpret_cast<u16x4*>(Bs + lofs[it]) = cvt4_bf16(stB[it]);
        }
        if (kt + 1 < 12) {
            const int dA = ((kt+1) >> 2) * (IMGW*IMGW) + ((kt+1) & 3) * (4*IMGW);
            const int dB = (kt+1) * 64;
#pragma unroll
            for (int it = 0; it < 8; ++it) {
                stA[it] = *reinterpret_cast<const f32x4*>(xin + boffA[it] + dA);
                stB[it] = *reinterpret_cast<const f32x4*>(Wm + boffB[it] + dB);
            }
        }
        __syncthreads();
#pragma unroll
        for (int ko = 0; ko < 2; ++ko) {
            const int colb = ko*64 + fq*16;
            bf16x8 af[4], bf4[4];
#pragma unroll
            for (int i = 0; i < 4; ++i) {
                af[i]  = *reinterpret_cast<const bf16x8*>(As + (wr*64 + i*16 + fr)*128 + (colb ^ xorv));
                bf4[i] = *reinterpret_cast<const bf16x8*>(Bs + (wc*64 + i*16 + fr)*128 + (colb ^ xorv));
            }
#pragma unroll
            for (int mi = 0; mi < 4; ++mi)
#pragma unroll
                for (int ni = 0; ni < 4; ++ni)
                    acc[mi][ni] = __builtin_amdgcn_mfma_f32_16x16x32_bf16(
                        af[mi], bf4[ni], acc[mi][ni], 0, 0, 0);
        }
    }

#pragma unroll
    for (int ni = 0; ni < 4; ++ni) {
        const int col = n0 + wc*64 + ni*16 + fr;
        const float bv = bias[col];
#pragma unroll
        for (int mi = 0; mi < 4; ++mi) {
            const int rowb = m0 + wr*64 + mi*16 + fq*4;
#pragma unroll
            for (int r = 0; r < 4; ++r)
                oo[(size_t)(rowb + r)*EMBD + col] = acc[mi][ni][r] + bv;
        }
    }
}

// ---------------- masked per-channel stats ----------------------------------
__global__ void stats_kernel(const float* __restrict__ o1, const float* __restrict__ o2,
                             float* __restrict__ ws) {
    const int b = blockIdx.y;
    const int c = blockIdx.x * 256 + threadIdx.x;

    float g1[4], g2[4];
#pragma unroll
    for (int i = 0; i < 4; ++i) { g1[i] = ws[WS_G1 + b*4 + i]; g2[i] = ws[WS_G2 + b*4 + i]; }

    for (int t = 0; t < 2; ++t) {
        const float* f = t ? o2 : o1;
        const float* g = t ? g2 : g1;
        int xlo = max(0, (int)g[0]);
        int xhi = min(FS, (int)g[2]);
        int ylo = max(0, (int)g[1]);
        int yhi = min(FS, (int)g[3]);
        float s = 0.f, ss = 0.f;
        for (int py = ylo; py < yhi; ++py)
            for (int px = xlo; px < xhi; ++px) {
                float v = f[(size_t)(b*NPATCH + py*FS + px)*EMBD + c];
                s += v; ss += v*v;
            }
        int nx = xhi - xlo; if (nx < 0) nx = 0;
        int ny = yhi - ylo; if (ny < 0) ny = 0;
        float n = (float)(nx*ny);
        float mean = s / fmaxf(n, 1.f);
        float var = (ss - 2.f*mean*s + n*mean*mean) / fmaxf(n - 1.f, 1.f);
        float sd = sqrtf(fmaxf(var, 0.f));
        ws[(t ? WS_MEAN2 : WS_MEAN1) + b*EMBD + c] = mean;
        ws[(t ? WS_STD2 : WS_STD1) + b*EMBD + c] = sd;
    }
}

// ---------------- blend (read-own / write-own, race-free) -------------------
__global__ void blend_kernel(float* __restrict__ o1, float* __restrict__ o2,
                             const float* __restrict__ ws) {
    const int b = blockIdx.y;
    const int p = blockIdx.x;
    const int py = p / FS, px = p - py*FS;
    const float pxf = (float)px, pyf = (float)py;

    const float sk1 = ws[WS_SK1 + b];
    const float sk2 = ws[WS_SK2 + b];
    const bool in1 = (pxf >= ws[WS_G1 + b*4+0]) && (pxf < ws[WS_G1 + b*4+2]) &&
                     (pyf >= ws[WS_G1 + b*4+1]) && (pyf < ws[WS_G1 + b*4+3]);
    const bool in2 = (pxf >= ws[WS_G2 + b*4+0]) && (pxf < ws[WS_G2 + b*4+2]) &&
                     (pyf >= ws[WS_G2 + b*4+1]) && (pyf < ws[WS_G2 + b*4+3]);
    const bool do1 = (sk1 == 0.f) && in2;
    const bool do2 = (sk2 == 0.f) && in1;
    if (!do1 && !do2) return;

    const int c = threadIdx.x * 4;
    const size_t base = (size_t)(b*NPATCH + p)*EMBD + c;
    const f32x4 f1 = *reinterpret_cast<const f32x4*>(o1 + base);
    const f32x4 f2 = *reinterpret_cast<const f32x4*>(o2 + base);
    const f32x4 m1 = *reinterpret_cast<const f32x4*>(ws + WS_MEAN1 + b*EMBD + c);
    const f32x4 s1 = *reinterpret_cast<const f32x4*>(ws + WS_STD1  + b*EMBD + c);
    const f32x4 m2 = *reinterpret_cast<const f32x4*>(ws + WS_MEAN2 + b*EMBD + c);
    const f32x4 s2 = *reinterpret_cast<const f32x4*>(ws + WS_STD2  + b*EMBD + c);

    if (do1) {
        f32x4 r;
#pragma unroll
        for (int j = 0; j < 4; ++j)
            r[j] = (f2[j] - m2[j]) / (s2[j] + EPSV) * (s1[j] + EPSV) + m1[j];
        *reinterpret_cast<f32x4*>(o1 + base) = r;
    }
    if (do2) {
        f32x4 r;
#pragma unroll
        for (int j = 0; j < 4; ++j)
            r[j] = (f1[j] - m1[j]) / (s1[j] + EPSV) * (s2[j] + EPSV) + m2[j];
        *reinterpret_cast<f32x4*>(o2 + base) = r;
    }
}

extern "C" void kernel_launch(void* const* d_in, const int* in_sizes, int n_in,
                              void* d_out, int out_size, void* d_ws, size_t ws_size,
                              hipStream_t stream) {
    const float* x    = (const float*)d_in[0];
    const float* x2   = (const float*)d_in[1];
    const float* gt1  = (const float*)d_in[2];
    const float* gt2  = (const float*)d_in[3];
    const float* Wm   = (const float*)d_in[4];
    const float* bias = (const float*)d_in[5];
    float* out = (float*)d_out;
    float* ws  = (float*)d_ws;

    float* o1 = out;
    float* o2 = out + O2_OFS;
    float* g1n = out + G1_OFS;
    float* g2n = out + G2_OFS;

    boxes_kernel<<<1, 64, 0, stream>>>(gt1, gt2, g1n, g2n, ws);

    if (ws_size >= WS_NEED) {
        unsigned short* Wb = (unsigned short*)((char*)d_ws + WSB_W);
        cvt_w_kernel<<<288, 256, 0, stream>>>(Wm, Wb);
        fused_gemm_kernel<<<dim3(1728, 2), 512, 0, stream>>>(x, x2, Wb, bias, out);
    } else {
        embed_gemm_kernel<<<dim3(1728, 2), 256, 0, stream>>>(x, x2, Wm, bias, out);
    }

    stats_kernel<<<dim3(3, NB), 256, 0, stream>>>(o1, o2, ws);
    blend_kernel<<<dim3(NPATCH, NB), 192, 0, stream>>>(o1, o2, ws);
}

// Round 7
// 229.071 us; speedup vs baseline: 3.0057x; 1.2302x over previous
//
#include <hip/hip_runtime.h>
#include <hip/hip_bf16.h>

#define FS 24
#define NPATCH 576
#define EMBD 768
#define KDIM 768
#define NB 64
#define IMGW 384
#define MTOT (NB*NPATCH)       // 36864
#define EPSV 1e-4f

#define O2_OFS (MTOT*EMBD)     // 28311552
#define G1_OFS (2*O2_OFS)      // 56623104
#define G2_OFS (G1_OFS + NB*4)

// workspace float-region layout (float indices at byte offset 0)
#define WS_G1 0
#define WS_G2 256
#define WS_SK1 512
#define WS_SK2 576
#define WS_MEAN1 1024
#define WS_STD1 (WS_MEAN1 + NB*EMBD)
#define WS_MEAN2 (WS_STD1 + NB*EMBD)
#define WS_STD2 (WS_MEAN2 + NB*EMBD)

// bf16 W (linear [n][k]) at byte offset 1 MiB in ws
#define WSB_W  1048576ULL
#define WS_NEED (WSB_W + 1179648ULL)   // 2,228,224 B (proven available r4/r6)

typedef __attribute__((ext_vector_type(8))) short bf16x8;
typedef __attribute__((ext_vector_type(4))) unsigned short u16x4;
typedef __attribute__((ext_vector_type(8))) unsigned short u16x8;
typedef __attribute__((ext_vector_type(4))) float f32x4;

__device__ __forceinline__ u16x4 cvt4_bf16(f32x4 v) {
    u16x4 r;
#pragma unroll
    for (int j = 0; j < 4; ++j) r[j] = __builtin_bit_cast(unsigned short, (__bf16)v[j]);
    return r;
}

__device__ __forceinline__ bf16x8 cvt8_bf16(f32x4 lo, f32x4 hi) {
    u16x4 a = cvt4_bf16(lo), b = cvt4_bf16(hi);
    u16x8 v;
#pragma unroll
    for (int q = 0; q < 4; ++q) { v[q] = a[q]; v[q+4] = b[q]; }
    return __builtin_bit_cast(bf16x8, v);
}

__device__ __forceinline__ void gload16(const void* g, const void* l) {
    __builtin_amdgcn_global_load_lds(
        (const __attribute__((address_space(1))) unsigned int*)g,
        (__attribute__((address_space(3))) unsigned int*)l, 16, 0, 0);
}

// ---------------- boxes (exact f32 port) ------------------------------------
__device__ inline float occ_of(const float b1[4], const float b2[4]) {
    float ixmin = fmaxf(b1[0], b2[0]);
    float iymin = fmaxf(b1[1], b2[1]);
    float ixmax = fminf(b1[2], b2[2]);
    float iymax = fminf(b1[3], b2[3]);
    float iv = fmaxf(iymax - iymin, 0.f) * fmaxf(ixmax - ixmin, 0.f);
    float v1 = (b1[2] - b1[0]) * (b1[3] - b1[1]);
    return (iv + 1e-8f) / (v1 + 1e-8f);
}

__device__ inline void upd_box(const float* b1, const float* b2, float* o) {
    float x0 = b1[0], y0 = b1[1], x2 = b1[2], y2 = b1[3];
    float q0 = b2[0], q1 = b2[1], q2 = b2[2], q3 = b2[3];
    bool condA = (x0 >= q0) && (x2 <= q2);
    bool subA1 = (q1 <= y0) && (q3 > y0);
    bool a1 = condA && subA1;
    bool a2 = condA && !subA1 && (q3 >= y2) && (q1 < y2);
    bool condB = !condA && (y0 >= q1) && (y2 <= q3);
    bool subB1 = (q0 <= x0) && (q2 > x0);
    bool bb1 = condB && subB1;
    bool bb2 = condB && !subB1 && (q2 >= x2) && (q0 < x2);
    o[1] = a1 ? q3 : y0;
    o[3] = a2 ? q1 : y2;
    o[0] = bb1 ? q2 : x0;
    o[2] = bb2 ? q0 : x2;
}

__global__ void boxes_kernel(const float* __restrict__ gt1, const float* __restrict__ gt2,
                             float* __restrict__ gout1, float* __restrict__ gout2,
                             float* __restrict__ ws) {
    const int b = threadIdx.x;
    if (b >= NB) return;
    float g1[4], g2[4];
    {
        float p0 = gt1[b*4+0]*(float)IMGW, p1 = gt1[b*4+1]*(float)IMGW;
        float p2 = gt1[b*4+2]*(float)IMGW, p3 = gt1[b*4+3]*(float)IMGW;
        g1[0] = rintf(p0 / 16.f);
        g1[1] = rintf(p1 / 16.f);
        g1[2] = rintf((p0 + p2 - 1.f) / 16.f);
        g1[3] = rintf((p1 + p3 - 1.f) / 16.f);
    }
    {
        float p0 = gt2[b*4+0]*(float)IMGW, p1 = gt2[b*4+1]*(float)IMGW;
        float p2 = gt2[b*4+2]*(float)IMGW, p3 = gt2[b*4+3]*(float)IMGW;
        g2[0] = rintf(p0 / 16.f);
        g2[1] = rintf(p1 / 16.f);
        g2[2] = rintf((p0 + p2 - 1.f) / 16.f);
        g2[3] = rintf((p1 + p3 - 1.f) / 16.f);
    }
    float occ1 = occ_of(g1, g2), occ2 = occ_of(g2, g1);
    const float fsf = (float)FS;
    bool skip1 = (occ1 > 0.5f) || (g2[3] <= g2[1]) || (g2[2] <= g2[0]) ||
                 (g2[0] < 0.f) || (g2[1] < 0.f) || (g2[0] >= fsf) || (g2[1] >= fsf);
    bool skip2 = (occ2 > 0.5f) || (g1[3] <= g1[1]) || (g1[2] <= g1[0]) ||
                 (g1[0] < 0.f) || (g1[1] < 0.f) || (g1[0] >= fsf) || (g1[1] >= fsf);

    float n1[4], n2[4];
    upd_box(g1, g2, n1);
    upd_box(g2, g1, n2);
    if (skip1) { n1[0]=g1[0]; n1[1]=g1[1]; n1[2]=g1[2]; n1[3]=g1[3]; }
    if (skip2) { n2[0]=g2[0]; n2[1]=g2[1]; n2[2]=g2[2]; n2[3]=g2[3]; }

    gout1[b*4+0] = n1[0]; gout1[b*4+1] = n1[1];
    gout1[b*4+2] = n1[2] - n1[0]; gout1[b*4+3] = n1[3] - n1[1];
    gout2[b*4+0] = n2[0]; gout2[b*4+1] = n2[1];
    gout2[b*4+2] = n2[2] - n2[0]; gout2[b*4+3] = n2[3] - n2[1];

#pragma unroll
    for (int i = 0; i < 4; ++i) { ws[WS_G1 + b*4 + i] = g1[i]; ws[WS_G2 + b*4 + i] = g2[i]; }
    ws[WS_SK1 + b] = skip1 ? 1.f : 0.f;
    ws[WS_SK2 + b] = skip2 ? 1.f : 0.f;
}

// ---- pre-convert W f32 -> bf16, LINEAR [n][k] ------------------------------
__global__ void cvt_w_kernel(const float* __restrict__ Wm, unsigned short* __restrict__ Wb) {
    const int idx = blockIdx.x * 256 + threadIdx.x;   // 73728 chunks of 8
    const f32x4 a = *reinterpret_cast<const f32x4*>(Wm + idx*8);
    const f32x4 b = *reinterpret_cast<const f32x4*>(Wm + idx*8 + 4);
    u16x8 r;
    u16x4 lo = cvt4_bf16(a), hi = cvt4_bf16(b);
#pragma unroll
    for (int j = 0; j < 4; ++j) { r[j] = lo[j]; r[j+4] = hi[j]; }
    *reinterpret_cast<u16x8*>(Wb + idx*8) = r;
}

// ---- fused-im2col GEMM, m97 structure --------------------------------------
// 128x128 tile, BK=64, 4 waves (2x2), single-buffered LDS 48 KiB (A f32 32K +
// B bf16 16K) -> 3 blocks/CU. ALL staging via global_load_lds (0 staging regs,
// no in-loop VALU): A straight from x (per-lane im2col addresses), B from Wb.
// Swizzle: linear LDS dest + XOR-permuted per-lane SOURCE + same XOR on
// ds_read (rule 21). Barrier drains vmcnt; 3 resident blocks cover the stall.
__global__ __launch_bounds__(256, 3)
void gemm_direct_kernel(const float* __restrict__ x1, const float* __restrict__ xx2,
                        const unsigned short* __restrict__ Wb,
                        const float* __restrict__ bias,
                        float* __restrict__ out) {
    __shared__ __align__(16) unsigned char ldsA[32768];   // f32 [128 rows][64 k]
    __shared__ __align__(16) unsigned char ldsB[16384];   // bf16 [128 n][64 k]

    const float* __restrict__ xin = blockIdx.y ? xx2 : x1;
    float* __restrict__ oo = out + (size_t)blockIdx.y * (size_t)O2_OFS;

    const int bx = blockIdx.x;                 // 1728 = 8 * 216
    const int swz = (bx & 7) * 216 + (bx >> 3);
    const int mt = swz / 6;
    const int nt = swz - mt * 6;
    const int m0 = mt * 128;
    const int n0 = nt * 128;

    const int tid = threadIdx.x;

    // ---- A staging: 2048 slots of 16B (4 f32). slot s = tid + j*256.
    // row = (tid>>4)+j*16, pos = tid&15; source chunk = (pos&8)|((pos^row)&7).
    int aoff[8];
    {
        const int pos = tid & 15;
#pragma unroll
        for (int j = 0; j < 8; ++j) {
            const int row = (tid >> 4) + j*16;
            const int m = m0 + row;
            const int bb = m / NPATCH;
            const int p  = m - bb*NPATCH;
            const int py = p / FS, px = p - py*FS;
            const int cs = (pos & 8) | ((pos ^ row) & 7);
            aoff[j] = ((bb*3)*IMGW + py*16 + (cs >> 2)) * IMGW + px*16 + (cs & 3)*4;
        }
    }
    // ---- B staging: 1024 slots of 16B (8 bf16). slot s = tid + j*256.
    // row = (tid>>3)+j*32, pos = tid&7; source chunk = pos^(row&7).
    int boff[4];
    {
        const int posb = tid & 7;
#pragma unroll
        for (int j = 0; j < 4; ++j) {
            const int row = (tid >> 3) + j*32;
            boff[j] = (n0 + row)*KDIM + ((posb ^ (row & 7)) << 3);
        }
    }
    const int ldsuni = (tid & 192) * 16;       // wave-uniform dest base part

    f32x4 acc[4][4];
#pragma unroll
    for (int i = 0; i < 4; ++i)
#pragma unroll
        for (int j = 0; j < 4; ++j) acc[i][j] = (f32x4){0.f, 0.f, 0.f, 0.f};

    const int l  = tid & 63;
    const int wid = tid >> 6;
    const int wr = wid >> 1, wc = wid & 1;
    const int fr = l & 15, fq = l >> 4;

#pragma unroll
    for (int kt = 0; kt < 12; ++kt) {
        const int dA = (kt >> 2)*(IMGW*IMGW) + (kt & 3)*(4*IMGW);   // f32 elems
        __syncthreads();                       // previous compute done with LDS
#pragma unroll
        for (int j = 0; j < 8; ++j)
            gload16(xin + aoff[j] + dA, ldsA + ldsuni + j*4096);
#pragma unroll
        for (int j = 0; j < 4; ++j)
            gload16(Wb + boff[j] + kt*64, ldsB + ldsuni + j*4096);
        __syncthreads();                       // barrier drains vmcnt -> ready

#pragma unroll
        for (int ko = 0; ko < 2; ++ko) {
            // A frags: f32 pairs + cvt -> bf16x8
            bf16x8 af[4];
#pragma unroll
            for (int mi = 0; mi < 4; ++mi) {
                const int r = wr*64 + mi*16 + fr;
                const int base = r*256 + ko*128;
                const f32x4 lo = *reinterpret_cast<const f32x4*>(
                    ldsA + base + (((fq*2 + 0) ^ (r & 7)) << 4));
                const f32x4 hi = *reinterpret_cast<const f32x4*>(
                    ldsA + base + (((fq*2 + 1) ^ (r & 7)) << 4));
                af[mi] = cvt8_bf16(lo, hi);
            }
            // B frags: bf16 direct
            bf16x8 bfv[4];
#pragma unroll
            for (int ni = 0; ni < 4; ++ni) {
                const int rn = wc*64 + ni*16 + fr;
                bfv[ni] = *reinterpret_cast<const bf16x8*>(
                    ldsB + rn*128 + (((ko*4 + fq) ^ (rn & 7)) << 4));
            }
            __builtin_amdgcn_s_setprio(1);
#pragma unroll
            for (int mi = 0; mi < 4; ++mi)
#pragma unroll
                for (int ni = 0; ni < 4; ++ni)
                    acc[mi][ni] = __builtin_amdgcn_mfma_f32_16x16x32_bf16(
                        af[mi], bfv[ni], acc[mi][ni], 0, 0, 0);
            __builtin_amdgcn_s_setprio(0);
        }
    }

    // ---- epilogue (r0-proven mapping) ----
#pragma unroll
    for (int ni = 0; ni < 4; ++ni) {
        const int col = n0 + wc*64 + ni*16 + fr;
        const float bv = bias[col];
#pragma unroll
        for (int mi = 0; mi < 4; ++mi) {
            const int rowb = m0 + wr*64 + mi*16 + fq*4;
#pragma unroll
            for (int r = 0; r < 4; ++r)
                oo[(size_t)(rowb + r)*EMBD + col] = acc[mi][ni][r] + bv;
        }
    }
}

// ---------------- FALLBACK GEMM (round-0, known-good) -----------------------
__global__ __launch_bounds__(256, 2)
void embed_gemm_kernel(const float* __restrict__ x1, const float* __restrict__ xx2,
                       const float* __restrict__ Wm, const float* __restrict__ bias,
                       float* __restrict__ out) {
    __shared__ __align__(16) unsigned char As[128*64*2];
    __shared__ __align__(16) unsigned char Bs[128*64*2];

    const float* __restrict__ xin = blockIdx.y ? xx2 : x1;
    float* __restrict__ oo = out + (size_t)blockIdx.y * (size_t)O2_OFS;

    const int bx = blockIdx.x;
    const int swz = (bx & 7) * (1728/8) + (bx >> 3);
    const int mt = swz / 6;
    const int nt = swz - mt * 6;
    const int m0 = mt * 128;
    const int n0 = nt * 128;

    const int tid = threadIdx.x;

    int boffA[8], boffB[8], lofs[8];
#pragma unroll
    for (int it = 0; it < 8; ++it) {
        const int ci = tid + 256*it;
        const int row = ci >> 4, col4 = ci & 15;
        const int m = m0 + row;
        const int bb = m / NPATCH;
        const int p  = m - bb*NPATCH;
        const int py = p / FS, px = p - py*FS;
        boffA[it] = ((bb*3)*IMGW + py*16 + (col4 >> 2)) * IMGW + px*16 + (col4 & 3)*4;
        boffB[it] = (n0 + row)*KDIM + col4*4;
        lofs[it]  = (ci*8) ^ ((row & 7) << 4);
    }

    f32x4 acc[4][4];
#pragma unroll
    for (int i = 0; i < 4; ++i)
#pragma unroll
        for (int j = 0; j < 4; ++j) acc[i][j] = (f32x4){0.f, 0.f, 0.f, 0.f};

    f32x4 stA[8], stB[8];
#pragma unroll
    for (int it = 0; it < 8; ++it) {
        stA[it] = *reinterpret_cast<const f32x4*>(xin + boffA[it]);
        stB[it] = *reinterpret_cast<const f32x4*>(Wm + boffB[it]);
    }

    const int l  = tid & 63;
    const int wid = tid >> 6;
    const int wr = wid >> 1, wc = wid & 1;
    const int fr = l & 15, fq = l >> 4;
    const int xorv = (fr & 7) << 4;

    for (int kt = 0; kt < 12; ++kt) {
        __syncthreads();
#pragma unroll
        for (int it = 0; it < 8; ++it) {
            *reinterpret_cast<u16x4*>(As + lofs[it]) = cvt4_bf16(stA[it]);
            *reinterpret_cast<u16x4*>(Bs + lofs[it]) = cvt4_bf16(stB[it]);
        }
        if (kt + 1 < 12) {
            const int dA = ((kt+1) >> 2) * (IMGW*IMGW) + ((kt+1) & 3) * (4*IMGW);
            const int dB = (kt+1) * 64;
#pragma unroll
            for (int it = 0; it < 8; ++it) {
                stA[it] = *reinterpret_cast<const f32x4*>(xin + boffA[it] + dA);
                stB[it] = *reinterpret_cast<const f32x4*>(Wm + boffB[it] + dB);
            }
        }
        __syncthreads();
#pragma unroll
        for (int ko = 0; ko < 2; ++ko) {
            const int colb = ko*64 + fq*16;
            bf16x8 af[4], bf4[4];
#pragma unroll
            for (int i = 0; i < 4; ++i) {
                af[i]  = *reinterpret_cast<const bf16x8*>(As + (wr*64 + i*16 + fr)*128 + (colb ^ xorv));
                bf4[i] = *reinterpret_cast<const bf16x8*>(Bs + (wc*64 + i*16 + fr)*128 + (colb ^ xorv));
            }
#pragma unroll
            for (int mi = 0; mi < 4; ++mi)
#pragma unroll
                for (int ni = 0; ni < 4; ++ni)
                    acc[mi][ni] = __builtin_amdgcn_mfma_f32_16x16x32_bf16(
                        af[mi], bf4[ni], acc[mi][ni], 0, 0, 0);
        }
    }

#pragma unroll
    for (int ni = 0; ni < 4; ++ni) {
        const int col = n0 + wc*64 + ni*16 + fr;
        const float bv = bias[col];
#pragma unroll
        for (int mi = 0; mi < 4; ++mi) {
            const int rowb = m0 + wr*64 + mi*16 + fq*4;
#pragma unroll
            for (int r = 0; r < 4; ++r)
                oo[(size_t)(rowb + r)*EMBD + col] = acc[mi][ni][r] + bv;
        }
    }
}

// ---------------- masked per-channel stats ----------------------------------
__global__ void stats_kernel(const float* __restrict__ o1, const float* __restrict__ o2,
                             float* __restrict__ ws) {
    const int b = blockIdx.y;
    const int c = blockIdx.x * 256 + threadIdx.x;

    float g1[4], g2[4];
#pragma unroll
    for (int i = 0; i < 4; ++i) { g1[i] = ws[WS_G1 + b*4 + i]; g2[i] = ws[WS_G2 + b*4 + i]; }

    for (int t = 0; t < 2; ++t) {
        const float* f = t ? o2 : o1;
        const float* g = t ? g2 : g1;
        int xlo = max(0, (int)g[0]);
        int xhi = min(FS, (int)g[2]);
        int ylo = max(0, (int)g[1]);
        int yhi = min(FS, (int)g[3]);
        float s = 0.f, ss = 0.f;
        for (int py = ylo; py < yhi; ++py)
            for (int px = xlo; px < xhi; ++px) {
                float v = f[(size_t)(b*NPATCH + py*FS + px)*EMBD + c];
                s += v; ss += v*v;
            }
        int nx = xhi - xlo; if (nx < 0) nx = 0;
        int ny = yhi - ylo; if (ny < 0) ny = 0;
        float n = (float)(nx*ny);
        float mean = s / fmaxf(n, 1.f);
        float var = (ss - 2.f*mean*s + n*mean*mean) / fmaxf(n - 1.f, 1.f);
        float sd = sqrtf(fmaxf(var, 0.f));
        ws[(t ? WS_MEAN2 : WS_MEAN1) + b*EMBD + c] = mean;
        ws[(t ? WS_STD2 : WS_STD1) + b*EMBD + c] = sd;
    }
}

// ---------------- blend (read-own / write-own, race-free) -------------------
__global__ void blend_kernel(float* __restrict__ o1, float* __restrict__ o2,
                             const float* __restrict__ ws) {
    const int b = blockIdx.y;
    const int p = blockIdx.x;
    const int py = p / FS, px = p - py*FS;
    const float pxf = (float)px, pyf = (float)py;

    const float sk1 = ws[WS_SK1 + b];
    const float sk2 = ws[WS_SK2 + b];
    const bool in1 = (pxf >= ws[WS_G1 + b*4+0]) && (pxf < ws[WS_G1 + b*4+2]) &&
                     (pyf >= ws[WS_G1 + b*4+1]) && (pyf < ws[WS_G1 + b*4+3]);
    const bool in2 = (pxf >= ws[WS_G2 + b*4+0]) && (pxf < ws[WS_G2 + b*4+2]) &&
                     (pyf >= ws[WS_G2 + b*4+1]) && (pyf < ws[WS_G2 + b*4+3]);
    const bool do1 = (sk1 == 0.f) && in2;
    const bool do2 = (sk2 == 0.f) && in1;
    if (!do1 && !do2) return;

    const int c = threadIdx.x * 4;
    const size_t base = (size_t)(b*NPATCH + p)*EMBD + c;
    const f32x4 f1 = *reinterpret_cast<const f32x4*>(o1 + base);
    const f32x4 f2 = *reinterpret_cast<const f32x4*>(o2 + base);
    const f32x4 m1 = *reinterpret_cast<const f32x4*>(ws + WS_MEAN1 + b*EMBD + c);
    const f32x4 s1 = *reinterpret_cast<const f32x4*>(ws + WS_STD1  + b*EMBD + c);
    const f32x4 m2 = *reinterpret_cast<const f32x4*>(ws + WS_MEAN2 + b*EMBD + c);
    const f32x4 s2 = *reinterpret_cast<const f32x4*>(ws + WS_STD2  + b*EMBD + c);

    if (do1) {
        f32x4 r;
#pragma unroll
        for (int j = 0; j < 4; ++j)
            r[j] = (f2[j] - m2[j]) / (s2[j] + EPSV) * (s1[j] + EPSV) + m1[j];
        *reinterpret_cast<f32x4*>(o1 + base) = r;
    }
    if (do2) {
        f32x4 r;
#pragma unroll
        for (int j = 0; j < 4; ++j)
            r[j] = (f1[j] - m1[j]) / (s1[j] + EPSV) * (s2[j] + EPSV) + m2[j];
        *reinterpret_cast<f32x4*>(o2 + base) = r;
    }
}

extern "C" void kernel_launch(void* const* d_in, const int* in_sizes, int n_in,
                              void* d_out, int out_size, void* d_ws, size_t ws_size,
                              hipStream_t stream) {
    const float* x    = (const float*)d_in[0];
    const float* x2   = (const float*)d_in[1];
    const float* gt1  = (const float*)d_in[2];
    const float* gt2  = (const float*)d_in[3];
    const float* Wm   = (const float*)d_in[4];
    const float* bias = (const float*)d_in[5];
    float* out = (float*)d_out;
    float* ws  = (float*)d_ws;

    float* o1 = out;
    float* o2 = out + O2_OFS;
    float* g1n = out + G1_OFS;
    float* g2n = out + G2_OFS;

    boxes_kernel<<<1, 64, 0, stream>>>(gt1, gt2, g1n, g2n, ws);

    if (ws_size >= WS_NEED) {
        unsigned short* Wb = (unsigned short*)((char*)d_ws + WSB_W);
        cvt_w_kernel<<<288, 256, 0, stream>>>(Wm, Wb);
        gemm_direct_kernel<<<dim3(1728, 2), 256, 0, stream>>>(x, x2, Wb, bias, out);
    } else {
        embed_gemm_kernel<<<dim3(1728, 2), 256, 0, stream>>>(x, x2, Wm, bias, out);
    }

    stats_kernel<<<dim3(3, NB), 256, 0, stream>>>(o1, o2, ws);
    blend_kernel<<<dim3(NPATCH, NB), 192, 0, stream>>>(o1, o2, ws);
}